// Round 12
// baseline (848.129 us; speedup 1.0000x reference)
//
#include <hip/hip_runtime.h>

// SelfAttention2d: n=8, c=512, h=w=64, nh=8, dh=64
#define NB   8
#define CC   512
#define SS   4096
#define NHD  8
#define DH   64
#define FEAT 512
#define NPER (CC*SS)

typedef unsigned short ushort_t;
typedef __attribute__((ext_vector_type(8))) short bf16x8;
typedef __attribute__((ext_vector_type(4))) float f32x4;

__device__ inline float b2f(ushort_t h) {
    union { unsigned int u; float f; } v; v.u = ((unsigned int)h) << 16; return v.f;
}
__device__ inline ushort_t f2b(float f) {
    union { float f; unsigned int u; } v; v.f = f;
    unsigned int u = v.u;
    u += 0x7fffu + ((u >> 16) & 1u);
    return (ushort_t)(u >> 16);
}
__device__ inline void unpack8(uint4 v, ushort_t* us) {
    us[0] = v.x & 0xffff; us[1] = v.x >> 16;
    us[2] = v.y & 0xffff; us[3] = v.y >> 16;
    us[4] = v.z & 0xffff; us[5] = v.z >> 16;
    us[6] = v.w & 0xffff; us[7] = v.w >> 16;
}
__device__ inline float loadIn(const void* p, size_t idx, int isf) {
    return isf ? ((const float*)p)[idx] : b2f(((const ushort_t*)p)[idx]);
}
__device__ inline void load8(const void* p, size_t idx, int isf, float* f) {
    if (isf) {
        const float* q = (const float*)p + idx;
        float4 a = *(const float4*)q, b = *(const float4*)(q + 4);
        f[0]=a.x; f[1]=a.y; f[2]=a.z; f[3]=a.w; f[4]=b.x; f[5]=b.y; f[6]=b.z; f[7]=b.w;
    } else {
        uint4 v = *(const uint4*)((const ushort_t*)p + idx);
        ushort_t us[8]; unpack8(v, us);
        for (int j = 0; j < 8; ++j) f[j] = b2f(us[j]);
    }
}

// async global->LDS, 16B per lane; LDS dest is wave-uniform base + lane*16
typedef __attribute__((address_space(1))) const unsigned int gas_u32;
typedef __attribute__((address_space(3))) unsigned int las_u32;
__device__ inline void gload_lds16(const void* g, void* l) {
    __builtin_amdgcn_global_load_lds((gas_u32*)g, (las_u32*)l, 16, 0, 0);
}

// ---------------- K0: dtype probe (bf16 vs fp32 input storage) ----------------
__global__ void probe_kernel(const unsigned int* __restrict__ x, int* __restrict__ flag) {
    unsigned int w = x[threadIdx.x & 63];
    unsigned int elo = (w >> 7) & 0xFF;
    int hit = (elo >= 0x60 && elo <= 0x9F) ? 1 : 0;
    for (int m = 1; m < 64; m <<= 1) hit += __shfl_xor(hit, m, 64);
    if (threadIdx.x == 0) *flag = (hit >= 40) ? 0 : 1;
}

// ---------------- K1: ada = cond @ W_ada + b_ada (fp32 out) ----------------
__global__ __launch_bounds__(256) void ada_kernel(
    const void* __restrict__ cond, const void* __restrict__ W,
    const void* __restrict__ bias, float* __restrict__ out,
    const int* __restrict__ flagp)
{
    int isf = *flagp;
    int n = blockIdx.x;
    int j = blockIdx.y * 256 + threadIdx.x;
    float acc = loadIn(bias, j, isf);
    for (int k = 0; k < FEAT; ++k)
        acc += loadIn(cond, (size_t)n * FEAT + k, isf) * loadIn(W, (size_t)k * (2 * CC) + j, isf);
    out[n * (2 * CC) + j] = acc;
}

// ---------------- K2: per-sample partial sum/sumsq (pure overwrite, no atomics) ----
__global__ __launch_bounds__(256) void stats_kernel(
    const void* __restrict__ x, float* __restrict__ part, const int* __restrict__ flagp)
{
    int isf = *flagp;
    int n = blockIdx.x, blk = blockIdx.y;
    int tid = threadIdx.x;
    float s = 0.f, ss = 0.f;
    size_t base8 = (size_t)blk * 4096 + tid;
    for (int i = 0; i < 16; ++i) {
        float f[8];
        load8(x, ((size_t)n * NPER) + (base8 + (size_t)i * 256) * 8, isf, f);
        for (int j = 0; j < 8; ++j) { s += f[j]; ss += f[j] * f[j]; }
    }
    for (int m = 1; m < 64; m <<= 1) { s += __shfl_xor(s, m, 64); ss += __shfl_xor(ss, m, 64); }
    int w = tid >> 6;
    if ((tid & 63) == 0) {
        part[(size_t)n * 512 + (blk * 4 + w) * 2 + 0] = s;
        part[(size_t)n * 512 + (blk * 4 + w) * 2 + 1] = ss;
    }
}

// ---------------- K3: per-(n,c) affine a,b (deterministic tree reduction) -----
__global__ __launch_bounds__(256) void coef_kernel(
    const float* __restrict__ ada, const float* __restrict__ part,
    float* __restrict__ coefA, float* __restrict__ coefB)
{
    __shared__ float reds[4], redss[4], mv[2];
    int n = blockIdx.x;
    int tid = threadIdx.x;
    float s  = part[(size_t)n * 512 + tid * 2 + 0];
    float ss = part[(size_t)n * 512 + tid * 2 + 1];
    for (int m = 1; m < 64; m <<= 1) { s += __shfl_xor(s, m, 64); ss += __shfl_xor(ss, m, 64); }
    int w = tid >> 6, lane = tid & 63;
    if (lane == 0) { reds[w] = s; redss[w] = ss; }
    __syncthreads();
    if (tid == 0) {
        float S  = (reds[0] + reds[1]) + (reds[2] + reds[3]);
        float S2 = (redss[0] + redss[1]) + (redss[2] + redss[3]);
        float inv = 1.f / (float)NPER;
        float mean = S * inv;
        float var  = S2 * inv - mean * mean;
        mv[0] = mean;
        mv[1] = rsqrtf(var + 1e-5f);
    }
    __syncthreads();
    float mean = mv[0], r = mv[1];
    int c = blockIdx.y * 256 + tid;
    float a = (ada[n * (2 * CC) + c] + 1.f) * r;
    coefA[n * CC + c] = a;
    coefB[n * CC + c] = ada[n * (2 * CC) + CC + c] - mean * a;
}

// ---------------- K3b: W' = W_qkv * coefA (bf16), bias2 = b_qkv + W_qkv @ coefB ----
__global__ __launch_bounds__(256) void wprime_kernel(
    const void* __restrict__ W, const void* __restrict__ bias,
    const float* __restrict__ coefA, const float* __restrict__ coefB,
    ushort_t* __restrict__ Wp, float* __restrict__ bias2,
    const int* __restrict__ flagp)
{
    int isf = *flagp;
    int n = blockIdx.x;
    int o = blockIdx.y * 256 + threadIdx.x;          // 0..1535
    const float* cA = coefA + n * CC;
    const float* cB = coefB + n * CC;
    float bacc = loadIn(bias, o, isf);
    ushort_t* dst = Wp + ((size_t)n * 1536 + o) * 512;
    for (int c = 0; c < 512; c += 8) {
        float wv[8];
        load8(W, (size_t)o * 512 + c, isf, wv);
        float4 a0 = *(const float4*)&cA[c], a1 = *(const float4*)&cA[c + 4];
        float4 b0 = *(const float4*)&cB[c], b1 = *(const float4*)&cB[c + 4];
        float av[8] = {a0.x, a0.y, a0.z, a0.w, a1.x, a1.y, a1.z, a1.w};
        float bv[8] = {b0.x, b0.y, b0.z, b0.w, b1.x, b1.y, b1.z, b1.w};
        ushort_t pk[8];
        for (int j = 0; j < 8; ++j) {
            bacc += wv[j] * bv[j];
            pk[j] = f2b(wv[j] * av[j]);
        }
        *(ushort4*)&dst[c]     = make_ushort4(pk[0], pk[1], pk[2], pk[3]);
        *(ushort4*)&dst[c + 4] = make_ushort4(pk[4], pk[5], pk[6], pk[7]);
    }
    bias2[n * 1536 + o] = bacc;
}

// ---------------- K3c: W_out -> bf16 (one-time convert) ----------------
__global__ __launch_bounds__(256) void wconv_kernel(
    const void* __restrict__ W, ushort_t* __restrict__ Wb, const int* __restrict__ flagp)
{
    int isf = *flagp;
    size_t i = ((size_t)blockIdx.x * 256 + threadIdx.x) * 8;
    float f[8];
    load8(W, i, isf, f);
    ushort_t pk[8];
    for (int j = 0; j < 8; ++j) pk[j] = f2b(f[j]);
    *(ushort4*)&Wb[i]     = make_ushort4(pk[0], pk[1], pk[2], pk[3]);
    *(ushort4*)&Wb[i + 4] = make_ushort4(pk[4], pk[5], pk[6], pk[7]);
}

// ---------------- K3d: xt = transpose(x) as bf16 [n][s][c] ----------------
__global__ __launch_bounds__(256) void xt_kernel(
    const void* __restrict__ x, ushort_t* __restrict__ xt, const int* __restrict__ flagp)
{
    __shared__ __align__(16) short xl[64][72];
    int isf = *flagp;
    int st = blockIdx.x & 63, ct = blockIdx.x >> 6;
    int n = blockIdx.y;
    int s0 = st * 64, c0 = ct * 64;
    int tid = threadIdx.x;
    for (int it = 0; it < 2; ++it) {
        int t = tid + it * 256;
        int cr = t >> 3, sc8 = t & 7;
        float f[8];
        load8(x, ((size_t)n * CC + c0 + cr) * SS + s0 + sc8 * 8, isf, f);
        ushort_t pk[8];
        for (int j = 0; j < 8; ++j) pk[j] = f2b(f[j]);
        *(ushort4*)&xl[cr][sc8 * 8]     = make_ushort4(pk[0], pk[1], pk[2], pk[3]);
        *(ushort4*)&xl[cr][sc8 * 8 + 4] = make_ushort4(pk[4], pk[5], pk[6], pk[7]);
    }
    __syncthreads();
    for (int it = 0; it < 2; ++it) {
        int t = tid + it * 256;
        int sr = t >> 3, cc8 = t & 7;
        ushort_t pk[8];
        for (int j = 0; j < 8; ++j) pk[j] = (ushort_t)xl[cc8 * 8 + j][sr];
        size_t o = ((size_t)n * SS + s0 + sr) * CC + c0 + cc8 * 8;
        *(ushort4*)&xt[o]     = make_ushort4(pk[0], pk[1], pk[2], pk[3]);
        *(ushort4*)&xt[o + 4] = make_ushort4(pk[4], pk[5], pk[6], pk[7]);
    }
}

// ---------------- K4: qkv GEMM v3 (unchanged from R11) ----------
__global__ __launch_bounds__(256) void qkv_gemm_kernel(
    const ushort_t* __restrict__ Wp, const ushort_t* __restrict__ xt,
    const float* __restrict__ bias2, ushort_t* __restrict__ C,
    int nb, int hb, int hc)
{
    __shared__ __align__(16) short Alds[3][64][64];
    __shared__ __align__(16) short Blds[64][64];
    int z = blockIdx.x;
    int nIdx = nb + z;
    int n0 = blockIdx.y * 64;
    int hh = blockIdx.z;
    int head = hb + hh;
    int hcc = hc * 64;
    int tid = threadIdx.x;
    int w = tid >> 6, lane = tid & 63;
    int quad = lane >> 4, l16 = lane & 15;
    int wm = (w >> 1) * 32, wn = (w & 1) * 32;
    const ushort_t* Ab = Wp + ((size_t)nIdx * 1536 + head * 64) * 512;
    const ushort_t* Bb = xt + ((size_t)nIdx * SS + n0) * 512;
    f32x4 acc[3][2][2] = {};

    int chunk0 = tid, chunk1 = tid + 256;
    int row0 = chunk0 >> 3, ssl0 = (chunk0 & 7) ^ (row0 & 7);
    int row1 = chunk1 >> 3, ssl1 = (chunk1 & 7) ^ (row1 & 7);
    int cb0a = w * 64, cb0b = 256 + w * 64;

    for (int k0 = 0; k0 < 512; k0 += 64) {
        __syncthreads();
        gload_lds16(&Bb[(size_t)row0 * 512 + k0 + ssl0 * 8], (short*)Blds + cb0a * 8);
        gload_lds16(&Bb[(size_t)row1 * 512 + k0 + ssl1 * 8], (short*)Blds + cb0b * 8);
        #pragma unroll
        for (int p = 0; p < 3; ++p) {
            const ushort_t* Ap = Ab + (size_t)p * 512 * 512;
            gload_lds16(&Ap[(size_t)row0 * 512 + k0 + ssl0 * 8], (short*)Alds[p] + cb0a * 8);
            gload_lds16(&Ap[(size_t)row1 * 512 + k0 + ssl1 * 8], (short*)Alds[p] + cb0b * 8);
        }
        __syncthreads();   // drains vmcnt before reads; also protects reuse
        for (int kk = 0; kk < 2; ++kk) {
            bf16x8 bfv[2];
            for (int ni = 0; ni < 2; ++ni)
                bfv[ni] = *(const bf16x8*)&Blds[wn + ni * 16 + l16]
                                               [((kk * 4 + quad) ^ (l16 & 7)) * 8];
            #pragma unroll
            for (int p = 0; p < 3; ++p) {
                bf16x8 af[2];
                for (int mi = 0; mi < 2; ++mi)
                    af[mi] = *(const bf16x8*)&Alds[p][wm + mi * 16 + l16]
                                                     [((kk * 4 + quad) ^ (l16 & 7)) * 8];
                for (int mi = 0; mi < 2; ++mi)
                    for (int ni = 0; ni < 2; ++ni)
                        acc[p][mi][ni] = __builtin_amdgcn_mfma_f32_16x16x32_bf16(
                            af[mi], bfv[ni], acc[p][mi][ni], 0, 0, 0);
            }
        }
    }

    const float* b2p = bias2 + (size_t)nIdx * 1536;
    #pragma unroll
    for (int p = 0; p < 3; ++p) {
        int arow0 = p * 512 + head * 64;
        size_t cbase = ((size_t)(z * 3 + p) * hcc + hh * 64) * SS;
        if (p < 2) {
            const float SCL = 0.42467078f;   // dh^-0.25 * sqrt(log2 e)
            for (int mi = 0; mi < 2; ++mi)
                for (int ni = 0; ni < 2; ++ni) {
                    int col = n0 + wn + ni * 16 + l16;
                    int d0 = wm + mi * 16 + quad * 4;
                    ushort_t pk[4];
                    for (int r = 0; r < 4; ++r) {
                        float v = (acc[p][mi][ni][r] + b2p[arow0 + d0 + r]) * SCL;
                        pk[r] = f2b(v);
                    }
                    *(ushort4*)&C[cbase + (size_t)col * 64 + d0] =
                        make_ushort4(pk[0], pk[1], pk[2], pk[3]);
                }
        } else {
            for (int mi = 0; mi < 2; ++mi)
                for (int ni = 0; ni < 2; ++ni) {
                    int col = n0 + wn + ni * 16 + l16;
                    for (int r = 0; r < 4; ++r) {
                        int rowl = wm + mi * 16 + quad * 4 + r;
                        float v = acc[p][mi][ni][r] + b2p[arow0 + rowl];
                        C[cbase + (size_t)rowl * SS + col] = f2b(v);
                    }
                }
        }
    }
}

// ---------------- K5: MFMA flash attention v7 ----------------
// v6 compute; each block now handles TWO s-tiles sequentially (sh loop) so the
// grid (1024 blocks) fits in one uniform residency round (4 blocks/CU, LDS-cap
// 5) with zero ragged tail -- v6's 2048 blocks gave 1.6 rounds and 38% achieved
// occupancy. K/V re-streamed per sh; qkv is L3-resident so HBM FETCH unchanged.
__global__ __launch_bounds__(256, 4) void attn_kernel(
    const ushort_t* __restrict__ qkv,
    ushort_t* __restrict__ y,            // ybuf [n][CC][SS]
    int nb, int hb, int hc)
{
    __shared__ __align__(16) short Klds[2][64][64];
    __shared__ __align__(16) short Vlds[2][64][64];

    int hl = blockIdx.y;
    int z = blockIdx.z;
    int n = nb + z;
    int hcc = hc * 64;
    const ushort_t* Q = qkv + ((size_t)(z * 3 + 0) * hcc + hl * 64) * SS;
    const ushort_t* K = qkv + ((size_t)(z * 3 + 1) * hcc + hl * 64) * SS;
    const ushort_t* V = qkv + ((size_t)(z * 3 + 2) * hcc + hl * 64) * SS;

    int tid = threadIdx.x;
    int w = tid >> 6, lane = tid & 63;
    int quad = lane >> 4, l16 = lane & 15;
    int sw = l16 & 7;

    auto stage = [&](int b, int tt) {
        #pragma unroll
        for (int it = 0; it < 2; ++it) {
            int chunk = it * 256 + tid;
            int row = chunk >> 3;
            int ssl = (chunk & 7) ^ (row & 7);
            int cb0 = it * 256 + w * 64;
            gload_lds16(&K[(size_t)(tt + row) * 64 + ssl * 8], (short*)Klds[b] + cb0 * 8);
            gload_lds16(&V[(size_t)row * SS + tt + ssl * 8],   (short*)Vlds[b] + cb0 * 8);
        }
    };

    const short ONE = 0x3F80;
    bf16x8 ones = { ONE, ONE, ONE, ONE, ONE, ONE, ONE, ONE };

    for (int sh = 0; sh < 2; ++sh) {
        int s0 = (blockIdx.x * 2 + sh) * 128;

        bf16x8 qf[2][2];
        for (int si = 0; si < 2; ++si)
            for (int kk = 0; kk < 2; ++kk)
                qf[si][kk] = *(const bf16x8*)&Q[(size_t)(s0 + w * 32 + si * 16 + l16) * 64
                                                + kk * 32 + quad * 8];

        f32x4 o[2][4] = {};
        f32x4 sum_acc[2] = {};

        stage(0, 0);

        for (int t0 = 0; t0 < SS; t0 += 64) {
            int cur = (t0 >> 6) & 1;
            __syncthreads();
            if (t0 + 64 < SS) stage(cur ^ 1, t0 + 64);

            for (int kk = 0; kk < 2; ++kk) {
                f32x4 sv[2][2];
                for (int ntl = 0; ntl < 2; ++ntl) {
                    int nt = kk * 2 + ntl;
                    bf16x8 kf0 = *(const bf16x8*)&Klds[cur][nt * 16 + l16][((0 * 4 + quad) ^ sw) * 8];
                    bf16x8 kf1 = *(const bf16x8*)&Klds[cur][nt * 16 + l16][((1 * 4 + quad) ^ sw) * 8];
                    for (int si = 0; si < 2; ++si) {
                        f32x4 a = { -16.f, -16.f, -16.f, -16.f };
                        a = __builtin_amdgcn_mfma_f32_16x16x32_bf16(kf0, qf[si][0], a, 0, 0, 0);
                        a = __builtin_amdgcn_mfma_f32_16x16x32_bf16(kf1, qf[si][1], a, 0, 0, 0);
                        sv[ntl][si] = a;
                    }
                }

                bf16x8 vf[4];
                for (int dt = 0; dt < 4; ++dt)
                    vf[dt] = *(const bf16x8*)&Vlds[cur][dt * 16 + l16][((kk * 4 + quad) ^ sw) * 8];

                for (int si = 0; si < 2; ++si) {
                    float p0 = exp2f(sv[0][si][0]), p1 = exp2f(sv[0][si][1]);
                    float p2 = exp2f(sv[0][si][2]), p3 = exp2f(sv[0][si][3]);
                    float p4 = exp2f(sv[1][si][0]), p5 = exp2f(sv[1][si][1]);
                    float p6 = exp2f(sv[1][si][2]), p7 = exp2f(sv[1][si][3]);
                    unsigned int x0, x1, y0, y1;
                    asm("v_cvt_pk_bf16_f32 %0, %1, %2" : "=v"(x0) : "v"(p0), "v"(p1));
                    asm("v_cvt_pk_bf16_f32 %0, %1, %2" : "=v"(x1) : "v"(p2), "v"(p3));
                    asm("v_cvt_pk_bf16_f32 %0, %1, %2" : "=v"(y0) : "v"(p4), "v"(p5));
                    asm("v_cvt_pk_bf16_f32 %0, %1, %2" : "=v"(y1) : "v"(p6), "v"(p7));
                    asm("v_permlane32_swap_b32 %0, %1" : "+v"(x0), "+v"(y0));
                    asm("v_permlane32_swap_b32 %0, %1" : "+v"(x1), "+v"(y1));
                    asm("v_permlane16_swap_b32 %0, %1" : "+v"(x0), "+v"(y0));
                    asm("v_permlane16_swap_b32 %0, %1" : "+v"(x1), "+v"(y1));
                    union { unsigned int u[4]; bf16x8 v; } frag;
                    frag.u[0] = x0; frag.u[1] = x1; frag.u[2] = y0; frag.u[3] = y1;

                    sum_acc[si] = __builtin_amdgcn_mfma_f32_16x16x32_bf16(frag.v, ones, sum_acc[si], 0, 0, 0);
                    for (int dt = 0; dt < 4; ++dt)
                        o[si][dt] = __builtin_amdgcn_mfma_f32_16x16x32_bf16(frag.v, vf[dt], o[si][dt], 0, 0, 0);
                }
            }
        }

        for (int si = 0; si < 2; ++si) {
            f32x4 inv;
            for (int r = 0; r < 4; ++r) inv[r] = 1.0f / sum_acc[si][r];
            for (int dt = 0; dt < 4; ++dt) {
                int d = dt * 16 + l16;
                int cidx = (hb + hl) * DH + d;
                size_t bidx = ((size_t)n * CC + cidx) * SS + s0 + w * 32 + si * 16 + quad * 4;
                ushort_t pk[4];
                for (int r = 0; r < 4; ++r) pk[r] = f2b(o[si][dt][r] * inv[r]);
                *(ushort4*)&y[bidx] = make_ushort4(pk[0], pk[1], pk[2], pk[3]);
            }
        }
    }
}

// ---------------- K6: out GEMM v2 (unchanged) ----------------
__global__ __launch_bounds__(512) void out_gemm_kernel(
    const ushort_t* __restrict__ Wb, const void* __restrict__ bias, const void* __restrict__ x,
    const ushort_t* __restrict__ ybuf, float* __restrict__ out,
    const int* __restrict__ flagp)
{
    __shared__ __align__(16) short Ylds[64][264];
    int isf = *flagp;
    int n = blockIdx.y;
    int s0 = blockIdx.x * 64;
    int tid = threadIdx.x;
    int w = tid >> 6, lane = tid & 63;
    int quad = lane >> 4, l16 = lane & 15;
    const ushort_t* Yb = ybuf + (size_t)n * ((size_t)CC * SS);
    float* Op = out + (size_t)n * NPER;

    f32x4 acc[4][4] = {};
    for (int kh = 0; kh < 2; ++kh) {
        __syncthreads();
        int ch = (tid & 255) + kh * 256;
        int cg = tid >> 8;
        for (int cb = 0; cb < 4; ++cb) {
            uint4 v = *(const uint4*)&Yb[(size_t)ch * SS + s0 + cg * 32 + cb * 8];
            ushort_t us[8]; unpack8(v, us);
            for (int j = 0; j < 8; ++j) Ylds[cg * 32 + cb * 8 + j][tid & 255] = (short)us[j];
        }
        __syncthreads();
        for (int k0 = 0; k0 < 256; k0 += 32) {
            bf16x8 af[4];
            for (int mi = 0; mi < 4; ++mi)
                af[mi] = *(const bf16x8*)&Wb[(size_t)(w * 64 + mi * 16 + l16) * 512
                                             + kh * 256 + k0 + quad * 8];
            for (int ni = 0; ni < 4; ++ni) {
                bf16x8 bfv = *(const bf16x8*)&Ylds[ni * 16 + l16][k0 + quad * 8];
                for (int mi = 0; mi < 4; ++mi)
                    acc[mi][ni] = __builtin_amdgcn_mfma_f32_16x16x32_bf16(
                        af[mi], bfv, acc[mi][ni], 0, 0, 0);
            }
        }
    }

    for (int mi = 0; mi < 4; ++mi)
        for (int ni = 0; ni < 4; ++ni) {
            int col = s0 + ni * 16 + l16;
            for (int r = 0; r < 4; ++r) {
                int m = w * 64 + mi * 16 + quad * 4 + r;
                size_t idx = (size_t)m * SS + col;
                float v = acc[mi][ni][r] + loadIn(bias, m, isf)
                        + loadIn(x, (size_t)n * NPER + idx, isf);
                Op[idx] = v;
            }
        }
}

extern "C" void kernel_launch(void* const* d_in, const int* in_sizes, int n_in,
                              void* d_out, int out_size, void* d_ws, size_t ws_size,
                              hipStream_t stream) {
    (void)in_sizes; (void)n_in; (void)out_size;
    const void* x     = d_in[0];
    const void* cond  = d_in[1];
    const void* W_ada = d_in[2];
    const void* b_ada = d_in[3];
    const void* W_qkv = d_in[4];
    const void* b_qkv = d_in[5];
    const void* W_out = d_in[6];
    const void* b_out = d_in[7];
    float* out = (float*)d_out;

    char* ws = (char*)d_ws;
    float* part   = (float*)ws;                        // 16,384 B
    float* ada    = (float*)(ws + 16384);              // 32,768 B
    float* coefA  = (float*)(ws + 49152);              // 16,384 B
    float* coefB  = (float*)(ws + 65536);              // 16,384 B
    int*   flag   = (int*)(ws + 81920);                // 256 B
    ushort_t* woutb  = (ushort_t*)(ws + 82176);        // 524,288 B
    float* bias2  = (float*)(ws + 606464);             // 49,152 B
    ushort_t* wprime = (ushort_t*)(ws + 655616);       // 12,582,912 B
    ushort_t* ybuf   = (ushort_t*)(ws + 13238528);     // 33,554,432 B
    ushort_t* xtb    = (ushort_t*)(ws + 46792960);     // 33,554,432 B
    const size_t BASE = 46792960ULL + 33554432ULL;     // 80,347,392
    ushort_t* qkvbuf = (ushort_t*)(ws + BASE);

    const size_t PER_HS = (size_t)3 * 64 * SS * 2;     // 1,572,864 per (sample, head)
    size_t avail = ws_size > BASE ? ws_size - BASE : 0;
    int NC = 1, HC = 1;
    if      (avail >= 64 * PER_HS) { NC = 8; HC = 8; }
    else if (avail >= 32 * PER_HS) { NC = 4; HC = 8; }
    else if (avail >= 16 * PER_HS) { NC = 2; HC = 8; }
    else if (avail >=  8 * PER_HS) { NC = 1; HC = 8; }
    else if (avail >=  4 * PER_HS) { NC = 1; HC = 4; }
    else if (avail >=  2 * PER_HS) { NC = 1; HC = 2; }

    probe_kernel <<<1, 64, 0, stream>>>((const unsigned int*)x, flag);
    ada_kernel   <<<dim3(NB, 4),  256, 0, stream>>>(cond, W_ada, b_ada, ada, flag);
    stats_kernel <<<dim3(NB, 64), 256, 0, stream>>>(x, part, flag);
    coef_kernel  <<<dim3(NB, 2),  256, 0, stream>>>(ada, part, coefA, coefB);
    wprime_kernel<<<dim3(NB, 6),  256, 0, stream>>>(W_qkv, b_qkv, coefA, coefB, wprime, bias2, flag);
    wconv_kernel <<<dim3(128),    256, 0, stream>>>(W_out, woutb, flag);
    xt_kernel    <<<dim3(512, NB), 256, 0, stream>>>(x, xtb, flag);

    for (int nb = 0; nb < NB; nb += NC)
        for (int hb = 0; hb < NHD; hb += HC) {
            qkv_gemm_kernel<<<dim3(NC, 64, HC), 256, 0, stream>>>(
                wprime, xtb, bias2, qkvbuf, nb, hb, HC);
            attn_kernel<<<dim3(16, HC, NC), 256, 0, stream>>>(
                qkvbuf, ybuf, nb, hb, HC);
        }

    out_gemm_kernel<<<dim3(64, NB), 512, 0, stream>>>(woutb, b_out, x, ybuf, out, flag);
}

// Round 13
// 820.775 us; speedup vs baseline: 1.0333x; 1.0333x over previous
//
#include <hip/hip_runtime.h>

// SelfAttention2d: n=8, c=512, h=w=64, nh=8, dh=64
#define NB   8
#define CC   512
#define SS   4096
#define NHD  8
#define DH   64
#define FEAT 512
#define NPER (CC*SS)

typedef unsigned short ushort_t;
typedef __attribute__((ext_vector_type(8))) short bf16x8;
typedef __attribute__((ext_vector_type(4))) float f32x4;

__device__ inline float b2f(ushort_t h) {
    union { unsigned int u; float f; } v; v.u = ((unsigned int)h) << 16; return v.f;
}
__device__ inline ushort_t f2b(float f) {
    union { float f; unsigned int u; } v; v.f = f;
    unsigned int u = v.u;
    u += 0x7fffu + ((u >> 16) & 1u);
    return (ushort_t)(u >> 16);
}
__device__ inline void unpack8(uint4 v, ushort_t* us) {
    us[0] = v.x & 0xffff; us[1] = v.x >> 16;
    us[2] = v.y & 0xffff; us[3] = v.y >> 16;
    us[4] = v.z & 0xffff; us[5] = v.z >> 16;
    us[6] = v.w & 0xffff; us[7] = v.w >> 16;
}
__device__ inline float loadIn(const void* p, size_t idx, int isf) {
    return isf ? ((const float*)p)[idx] : b2f(((const ushort_t*)p)[idx]);
}
__device__ inline void load8(const void* p, size_t idx, int isf, float* f) {
    if (isf) {
        const float* q = (const float*)p + idx;
        float4 a = *(const float4*)q, b = *(const float4*)(q + 4);
        f[0]=a.x; f[1]=a.y; f[2]=a.z; f[3]=a.w; f[4]=b.x; f[5]=b.y; f[6]=b.z; f[7]=b.w;
    } else {
        uint4 v = *(const uint4*)((const ushort_t*)p + idx);
        ushort_t us[8]; unpack8(v, us);
        for (int j = 0; j < 8; ++j) f[j] = b2f(us[j]);
    }
}

// async global->LDS, 16B per lane; LDS dest is wave-uniform base + lane*16
typedef __attribute__((address_space(1))) const unsigned int gas_u32;
typedef __attribute__((address_space(3))) unsigned int las_u32;
__device__ inline void gload_lds16(const void* g, void* l) {
    __builtin_amdgcn_global_load_lds((gas_u32*)g, (las_u32*)l, 16, 0, 0);
}

// ---------------- K0: dtype probe (bf16 vs fp32 input storage) ----------------
__global__ void probe_kernel(const unsigned int* __restrict__ x, int* __restrict__ flag) {
    unsigned int w = x[threadIdx.x & 63];
    unsigned int elo = (w >> 7) & 0xFF;
    int hit = (elo >= 0x60 && elo <= 0x9F) ? 1 : 0;
    for (int m = 1; m < 64; m <<= 1) hit += __shfl_xor(hit, m, 64);
    if (threadIdx.x == 0) *flag = (hit >= 40) ? 0 : 1;
}

// ---------------- K1: ada = cond @ W_ada + b_ada (fp32 out) ----------------
__global__ __launch_bounds__(256) void ada_kernel(
    const void* __restrict__ cond, const void* __restrict__ W,
    const void* __restrict__ bias, float* __restrict__ out,
    const int* __restrict__ flagp)
{
    int isf = *flagp;
    int n = blockIdx.x;
    int j = blockIdx.y * 256 + threadIdx.x;
    float acc = loadIn(bias, j, isf);
    for (int k = 0; k < FEAT; ++k)
        acc += loadIn(cond, (size_t)n * FEAT + k, isf) * loadIn(W, (size_t)k * (2 * CC) + j, isf);
    out[n * (2 * CC) + j] = acc;
}

// ---------------- K2: per-sample partial sum/sumsq (pure overwrite, no atomics) ----
__global__ __launch_bounds__(256) void stats_kernel(
    const void* __restrict__ x, float* __restrict__ part, const int* __restrict__ flagp)
{
    int isf = *flagp;
    int n = blockIdx.x, blk = blockIdx.y;
    int tid = threadIdx.x;
    float s = 0.f, ss = 0.f;
    size_t base8 = (size_t)blk * 4096 + tid;
    for (int i = 0; i < 16; ++i) {
        float f[8];
        load8(x, ((size_t)n * NPER) + (base8 + (size_t)i * 256) * 8, isf, f);
        for (int j = 0; j < 8; ++j) { s += f[j]; ss += f[j] * f[j]; }
    }
    for (int m = 1; m < 64; m <<= 1) { s += __shfl_xor(s, m, 64); ss += __shfl_xor(ss, m, 64); }
    int w = tid >> 6;
    if ((tid & 63) == 0) {
        part[(size_t)n * 512 + (blk * 4 + w) * 2 + 0] = s;
        part[(size_t)n * 512 + (blk * 4 + w) * 2 + 1] = ss;
    }
}

// ---------------- K3: per-(n,c) affine a,b (deterministic tree reduction) -----
__global__ __launch_bounds__(256) void coef_kernel(
    const float* __restrict__ ada, const float* __restrict__ part,
    float* __restrict__ coefA, float* __restrict__ coefB)
{
    __shared__ float reds[4], redss[4], mv[2];
    int n = blockIdx.x;
    int tid = threadIdx.x;
    float s  = part[(size_t)n * 512 + tid * 2 + 0];
    float ss = part[(size_t)n * 512 + tid * 2 + 1];
    for (int m = 1; m < 64; m <<= 1) { s += __shfl_xor(s, m, 64); ss += __shfl_xor(ss, m, 64); }
    int w = tid >> 6, lane = tid & 63;
    if (lane == 0) { reds[w] = s; redss[w] = ss; }
    __syncthreads();
    if (tid == 0) {
        float S  = (reds[0] + reds[1]) + (reds[2] + reds[3]);
        float S2 = (redss[0] + redss[1]) + (redss[2] + redss[3]);
        float inv = 1.f / (float)NPER;
        float mean = S * inv;
        float var  = S2 * inv - mean * mean;
        mv[0] = mean;
        mv[1] = rsqrtf(var + 1e-5f);
    }
    __syncthreads();
    float mean = mv[0], r = mv[1];
    int c = blockIdx.y * 256 + tid;
    float a = (ada[n * (2 * CC) + c] + 1.f) * r;
    coefA[n * CC + c] = a;
    coefB[n * CC + c] = ada[n * (2 * CC) + CC + c] - mean * a;
}

// ---------------- K3b: W' = W_qkv * coefA (bf16), bias2 = b_qkv + W_qkv @ coefB ----
__global__ __launch_bounds__(256) void wprime_kernel(
    const void* __restrict__ W, const void* __restrict__ bias,
    const float* __restrict__ coefA, const float* __restrict__ coefB,
    ushort_t* __restrict__ Wp, float* __restrict__ bias2,
    const int* __restrict__ flagp)
{
    int isf = *flagp;
    int n = blockIdx.x;
    int o = blockIdx.y * 256 + threadIdx.x;          // 0..1535
    const float* cA = coefA + n * CC;
    const float* cB = coefB + n * CC;
    float bacc = loadIn(bias, o, isf);
    ushort_t* dst = Wp + ((size_t)n * 1536 + o) * 512;
    for (int c = 0; c < 512; c += 8) {
        float wv[8];
        load8(W, (size_t)o * 512 + c, isf, wv);
        float4 a0 = *(const float4*)&cA[c], a1 = *(const float4*)&cA[c + 4];
        float4 b0 = *(const float4*)&cB[c], b1 = *(const float4*)&cB[c + 4];
        float av[8] = {a0.x, a0.y, a0.z, a0.w, a1.x, a1.y, a1.z, a1.w};
        float bv[8] = {b0.x, b0.y, b0.z, b0.w, b1.x, b1.y, b1.z, b1.w};
        ushort_t pk[8];
        for (int j = 0; j < 8; ++j) {
            bacc += wv[j] * bv[j];
            pk[j] = f2b(wv[j] * av[j]);
        }
        *(ushort4*)&dst[c]     = make_ushort4(pk[0], pk[1], pk[2], pk[3]);
        *(ushort4*)&dst[c + 4] = make_ushort4(pk[4], pk[5], pk[6], pk[7]);
    }
    bias2[n * 1536 + o] = bacc;
}

// ---------------- K3c: W_out -> bf16 (one-time convert) ----------------
__global__ __launch_bounds__(256) void wconv_kernel(
    const void* __restrict__ W, ushort_t* __restrict__ Wb, const int* __restrict__ flagp)
{
    int isf = *flagp;
    size_t i = ((size_t)blockIdx.x * 256 + threadIdx.x) * 8;
    float f[8];
    load8(W, i, isf, f);
    ushort_t pk[8];
    for (int j = 0; j < 8; ++j) pk[j] = f2b(f[j]);
    *(ushort4*)&Wb[i]     = make_ushort4(pk[0], pk[1], pk[2], pk[3]);
    *(ushort4*)&Wb[i + 4] = make_ushort4(pk[4], pk[5], pk[6], pk[7]);
}

// ---------------- K3d: xt = transpose(x) as bf16 [n][s][c] ----------------
__global__ __launch_bounds__(256) void xt_kernel(
    const void* __restrict__ x, ushort_t* __restrict__ xt, const int* __restrict__ flagp)
{
    __shared__ __align__(16) short xl[64][72];
    int isf = *flagp;
    int st = blockIdx.x & 63, ct = blockIdx.x >> 6;
    int n = blockIdx.y;
    int s0 = st * 64, c0 = ct * 64;
    int tid = threadIdx.x;
    for (int it = 0; it < 2; ++it) {
        int t = tid + it * 256;
        int cr = t >> 3, sc8 = t & 7;
        float f[8];
        load8(x, ((size_t)n * CC + c0 + cr) * SS + s0 + sc8 * 8, isf, f);
        ushort_t pk[8];
        for (int j = 0; j < 8; ++j) pk[j] = f2b(f[j]);
        *(ushort4*)&xl[cr][sc8 * 8]     = make_ushort4(pk[0], pk[1], pk[2], pk[3]);
        *(ushort4*)&xl[cr][sc8 * 8 + 4] = make_ushort4(pk[4], pk[5], pk[6], pk[7]);
    }
    __syncthreads();
    for (int it = 0; it < 2; ++it) {
        int t = tid + it * 256;
        int sr = t >> 3, cc8 = t & 7;
        ushort_t pk[8];
        for (int j = 0; j < 8; ++j) pk[j] = (ushort_t)xl[cc8 * 8 + j][sr];
        size_t o = ((size_t)n * SS + s0 + sr) * CC + c0 + cc8 * 8;
        *(ushort4*)&xt[o]     = make_ushort4(pk[0], pk[1], pk[2], pk[3]);
        *(ushort4*)&xt[o + 4] = make_ushort4(pk[4], pk[5], pk[6], pk[7]);
    }
}

// ---------------- K4: qkv GEMM v3 (unchanged from R11) ----------
__global__ __launch_bounds__(256) void qkv_gemm_kernel(
    const ushort_t* __restrict__ Wp, const ushort_t* __restrict__ xt,
    const float* __restrict__ bias2, ushort_t* __restrict__ C,
    int nb, int hb, int hc)
{
    __shared__ __align__(16) short Alds[3][64][64];
    __shared__ __align__(16) short Blds[64][64];
    int z = blockIdx.x;
    int nIdx = nb + z;
    int n0 = blockIdx.y * 64;
    int hh = blockIdx.z;
    int head = hb + hh;
    int hcc = hc * 64;
    int tid = threadIdx.x;
    int w = tid >> 6, lane = tid & 63;
    int quad = lane >> 4, l16 = lane & 15;
    int wm = (w >> 1) * 32, wn = (w & 1) * 32;
    const ushort_t* Ab = Wp + ((size_t)nIdx * 1536 + head * 64) * 512;
    const ushort_t* Bb = xt + ((size_t)nIdx * SS + n0) * 512;
    f32x4 acc[3][2][2] = {};

    int chunk0 = tid, chunk1 = tid + 256;
    int row0 = chunk0 >> 3, ssl0 = (chunk0 & 7) ^ (row0 & 7);
    int row1 = chunk1 >> 3, ssl1 = (chunk1 & 7) ^ (row1 & 7);
    int cb0a = w * 64, cb0b = 256 + w * 64;

    for (int k0 = 0; k0 < 512; k0 += 64) {
        __syncthreads();
        gload_lds16(&Bb[(size_t)row0 * 512 + k0 + ssl0 * 8], (short*)Blds + cb0a * 8);
        gload_lds16(&Bb[(size_t)row1 * 512 + k0 + ssl1 * 8], (short*)Blds + cb0b * 8);
        #pragma unroll
        for (int p = 0; p < 3; ++p) {
            const ushort_t* Ap = Ab + (size_t)p * 512 * 512;
            gload_lds16(&Ap[(size_t)row0 * 512 + k0 + ssl0 * 8], (short*)Alds[p] + cb0a * 8);
            gload_lds16(&Ap[(size_t)row1 * 512 + k0 + ssl1 * 8], (short*)Alds[p] + cb0b * 8);
        }
        __syncthreads();   // drains vmcnt before reads; also protects reuse
        for (int kk = 0; kk < 2; ++kk) {
            bf16x8 bfv[2];
            for (int ni = 0; ni < 2; ++ni)
                bfv[ni] = *(const bf16x8*)&Blds[wn + ni * 16 + l16]
                                               [((kk * 4 + quad) ^ (l16 & 7)) * 8];
            #pragma unroll
            for (int p = 0; p < 3; ++p) {
                bf16x8 af[2];
                for (int mi = 0; mi < 2; ++mi)
                    af[mi] = *(const bf16x8*)&Alds[p][wm + mi * 16 + l16]
                                                     [((kk * 4 + quad) ^ (l16 & 7)) * 8];
                for (int mi = 0; mi < 2; ++mi)
                    for (int ni = 0; ni < 2; ++ni)
                        acc[p][mi][ni] = __builtin_amdgcn_mfma_f32_16x16x32_bf16(
                            af[mi], bfv[ni], acc[p][mi][ni], 0, 0, 0);
            }
        }
    }

    const float* b2p = bias2 + (size_t)nIdx * 1536;
    #pragma unroll
    for (int p = 0; p < 3; ++p) {
        int arow0 = p * 512 + head * 64;
        size_t cbase = ((size_t)(z * 3 + p) * hcc + hh * 64) * SS;
        if (p < 2) {
            const float SCL = 0.42467078f;   // dh^-0.25 * sqrt(log2 e)
            for (int mi = 0; mi < 2; ++mi)
                for (int ni = 0; ni < 2; ++ni) {
                    int col = n0 + wn + ni * 16 + l16;
                    int d0 = wm + mi * 16 + quad * 4;
                    ushort_t pk[4];
                    for (int r = 0; r < 4; ++r) {
                        float v = (acc[p][mi][ni][r] + b2p[arow0 + d0 + r]) * SCL;
                        pk[r] = f2b(v);
                    }
                    *(ushort4*)&C[cbase + (size_t)col * 64 + d0] =
                        make_ushort4(pk[0], pk[1], pk[2], pk[3]);
                }
        } else {
            for (int mi = 0; mi < 2; ++mi)
                for (int ni = 0; ni < 2; ++ni) {
                    int col = n0 + wn + ni * 16 + l16;
                    for (int r = 0; r < 4; ++r) {
                        int rowl = wm + mi * 16 + quad * 4 + r;
                        float v = acc[p][mi][ni][r] + b2p[arow0 + rowl];
                        C[cbase + (size_t)rowl * SS + col] = f2b(v);
                    }
                }
        }
    }
}

// ---------------- K5: MFMA flash attention v8 ----------------
// R11 structure exactly (single s-tile per block, grid 2048 -- the R12 2-tile
// variant doubled FETCH and regressed). Epilogue change only: write ybuf
// TRANSPOSED [n][s][c] (scalar ushort stores, 32/thread, epilogue-only) so
// out_gemm can read B-fragments directly from global with no LDS transpose.
__global__ __launch_bounds__(256, 4) void attn_kernel(
    const ushort_t* __restrict__ qkv,
    ushort_t* __restrict__ yt,           // yt [n][SS][CC]
    int nb, int hb, int hc)
{
    __shared__ __align__(16) short Klds[2][64][64];
    __shared__ __align__(16) short Vlds[2][64][64];

    int s0 = blockIdx.x * 128;
    int hl = blockIdx.y;
    int z = blockIdx.z;
    int n = nb + z;
    int hcc = hc * 64;
    const ushort_t* Q = qkv + ((size_t)(z * 3 + 0) * hcc + hl * 64) * SS;
    const ushort_t* K = qkv + ((size_t)(z * 3 + 1) * hcc + hl * 64) * SS;
    const ushort_t* V = qkv + ((size_t)(z * 3 + 2) * hcc + hl * 64) * SS;

    int tid = threadIdx.x;
    int w = tid >> 6, lane = tid & 63;
    int quad = lane >> 4, l16 = lane & 15;
    int sw = l16 & 7;

    bf16x8 qf[2][2];
    for (int si = 0; si < 2; ++si)
        for (int kk = 0; kk < 2; ++kk)
            qf[si][kk] = *(const bf16x8*)&Q[(size_t)(s0 + w * 32 + si * 16 + l16) * 64
                                            + kk * 32 + quad * 8];

    auto stage = [&](int b, int tt) {
        #pragma unroll
        for (int it = 0; it < 2; ++it) {
            int chunk = it * 256 + tid;
            int row = chunk >> 3;
            int ssl = (chunk & 7) ^ (row & 7);
            int cb0 = it * 256 + w * 64;
            gload_lds16(&K[(size_t)(tt + row) * 64 + ssl * 8], (short*)Klds[b] + cb0 * 8);
            gload_lds16(&V[(size_t)row * SS + tt + ssl * 8],   (short*)Vlds[b] + cb0 * 8);
        }
    };

    const short ONE = 0x3F80;
    bf16x8 ones = { ONE, ONE, ONE, ONE, ONE, ONE, ONE, ONE };

    f32x4 o[2][4] = {};
    f32x4 sum_acc[2] = {};

    stage(0, 0);

    for (int t0 = 0; t0 < SS; t0 += 64) {
        int cur = (t0 >> 6) & 1;
        __syncthreads();
        if (t0 + 64 < SS) stage(cur ^ 1, t0 + 64);

        for (int kk = 0; kk < 2; ++kk) {
            f32x4 sv[2][2];
            for (int ntl = 0; ntl < 2; ++ntl) {
                int nt = kk * 2 + ntl;
                bf16x8 kf0 = *(const bf16x8*)&Klds[cur][nt * 16 + l16][((0 * 4 + quad) ^ sw) * 8];
                bf16x8 kf1 = *(const bf16x8*)&Klds[cur][nt * 16 + l16][((1 * 4 + quad) ^ sw) * 8];
                for (int si = 0; si < 2; ++si) {
                    f32x4 a = { -16.f, -16.f, -16.f, -16.f };
                    a = __builtin_amdgcn_mfma_f32_16x16x32_bf16(kf0, qf[si][0], a, 0, 0, 0);
                    a = __builtin_amdgcn_mfma_f32_16x16x32_bf16(kf1, qf[si][1], a, 0, 0, 0);
                    sv[ntl][si] = a;
                }
            }

            bf16x8 vf[4];
            for (int dt = 0; dt < 4; ++dt)
                vf[dt] = *(const bf16x8*)&Vlds[cur][dt * 16 + l16][((kk * 4 + quad) ^ sw) * 8];

            for (int si = 0; si < 2; ++si) {
                float p0 = exp2f(sv[0][si][0]), p1 = exp2f(sv[0][si][1]);
                float p2 = exp2f(sv[0][si][2]), p3 = exp2f(sv[0][si][3]);
                float p4 = exp2f(sv[1][si][0]), p5 = exp2f(sv[1][si][1]);
                float p6 = exp2f(sv[1][si][2]), p7 = exp2f(sv[1][si][3]);
                unsigned int x0, x1, y0, y1;
                asm("v_cvt_pk_bf16_f32 %0, %1, %2" : "=v"(x0) : "v"(p0), "v"(p1));
                asm("v_cvt_pk_bf16_f32 %0, %1, %2" : "=v"(x1) : "v"(p2), "v"(p3));
                asm("v_cvt_pk_bf16_f32 %0, %1, %2" : "=v"(y0) : "v"(p4), "v"(p5));
                asm("v_cvt_pk_bf16_f32 %0, %1, %2" : "=v"(y1) : "v"(p6), "v"(p7));
                asm("v_permlane32_swap_b32 %0, %1" : "+v"(x0), "+v"(y0));
                asm("v_permlane32_swap_b32 %0, %1" : "+v"(x1), "+v"(y1));
                asm("v_permlane16_swap_b32 %0, %1" : "+v"(x0), "+v"(y0));
                asm("v_permlane16_swap_b32 %0, %1" : "+v"(x1), "+v"(y1));
                union { unsigned int u[4]; bf16x8 v; } frag;
                frag.u[0] = x0; frag.u[1] = x1; frag.u[2] = y0; frag.u[3] = y1;

                sum_acc[si] = __builtin_amdgcn_mfma_f32_16x16x32_bf16(frag.v, ones, sum_acc[si], 0, 0, 0);
                for (int dt = 0; dt < 4; ++dt)
                    o[si][dt] = __builtin_amdgcn_mfma_f32_16x16x32_bf16(frag.v, vf[dt], o[si][dt], 0, 0, 0);
            }
        }
    }

    // Epilogue: write yt[n][s][c]  (c0 = head base; 32 scalar stores/thread)
    int c0 = (hb + hl) * DH;
    for (int si = 0; si < 2; ++si) {
        f32x4 inv;
        for (int r = 0; r < 4; ++r) inv[r] = 1.0f / sum_acc[si][r];
        for (int r = 0; r < 4; ++r) {
            size_t srow = (size_t)n * SS + s0 + w * 32 + si * 16 + quad * 4 + r;
            ushort_t* yp = yt + srow * CC + c0 + l16;
            for (int dt = 0; dt < 4; ++dt)
                yp[dt * 16] = f2b(o[si][dt][r] * inv[r]);
        }
    }
}

// ---------------- K6: out GEMM v3 -- B-fragments direct from yt [n][s][c] ------
// No LDS, no barriers: A (bf16 W_out) and B (yt) fragments both load straight
// from global; W is L2-resident, yt read exactly once per element.
__global__ __launch_bounds__(512) void out_gemm_kernel(
    const ushort_t* __restrict__ Wb, const void* __restrict__ bias, const void* __restrict__ x,
    const ushort_t* __restrict__ yt, float* __restrict__ out,
    const int* __restrict__ flagp)
{
    int isf = *flagp;
    int n = blockIdx.y;
    int s0 = blockIdx.x * 64;
    int tid = threadIdx.x;
    int w = tid >> 6, lane = tid & 63;
    int quad = lane >> 4, l16 = lane & 15;
    const ushort_t* Yt = yt + ((size_t)n * SS + s0) * CC;
    float* Op = out + (size_t)n * NPER;

    f32x4 acc[4][4] = {};
    for (int k0 = 0; k0 < 512; k0 += 32) {
        bf16x8 af[4], bfv[4];
        for (int mi = 0; mi < 4; ++mi)
            af[mi] = *(const bf16x8*)&Wb[(size_t)(w * 64 + mi * 16 + l16) * 512
                                         + k0 + quad * 8];
        for (int ni = 0; ni < 4; ++ni)
            bfv[ni] = *(const bf16x8*)&Yt[(size_t)(ni * 16 + l16) * CC + k0 + quad * 8];
        for (int ni = 0; ni < 4; ++ni)
            for (int mi = 0; mi < 4; ++mi)
                acc[mi][ni] = __builtin_amdgcn_mfma_f32_16x16x32_bf16(
                    af[mi], bfv[ni], acc[mi][ni], 0, 0, 0);
    }

    for (int mi = 0; mi < 4; ++mi)
        for (int ni = 0; ni < 4; ++ni) {
            int col = s0 + ni * 16 + l16;
            for (int r = 0; r < 4; ++r) {
                int m = w * 64 + mi * 16 + quad * 4 + r;
                size_t idx = (size_t)m * SS + col;
                float v = acc[mi][ni][r] + loadIn(bias, m, isf)
                        + loadIn(x, (size_t)n * NPER + idx, isf);
                Op[idx] = v;
            }
        }
}

extern "C" void kernel_launch(void* const* d_in, const int* in_sizes, int n_in,
                              void* d_out, int out_size, void* d_ws, size_t ws_size,
                              hipStream_t stream) {
    (void)in_sizes; (void)n_in; (void)out_size;
    const void* x     = d_in[0];
    const void* cond  = d_in[1];
    const void* W_ada = d_in[2];
    const void* b_ada = d_in[3];
    const void* W_qkv = d_in[4];
    const void* b_qkv = d_in[5];
    const void* W_out = d_in[6];
    const void* b_out = d_in[7];
    float* out = (float*)d_out;

    char* ws = (char*)d_ws;
    float* part   = (float*)ws;                        // 16,384 B
    float* ada    = (float*)(ws + 16384);              // 32,768 B
    float* coefA  = (float*)(ws + 49152);              // 16,384 B
    float* coefB  = (float*)(ws + 65536);              // 16,384 B
    int*   flag   = (int*)(ws + 81920);                // 256 B
    ushort_t* woutb  = (ushort_t*)(ws + 82176);        // 524,288 B
    float* bias2  = (float*)(ws + 606464);             // 49,152 B
    ushort_t* wprime = (ushort_t*)(ws + 655616);       // 12,582,912 B
    ushort_t* ybuf   = (ushort_t*)(ws + 13238528);     // 33,554,432 B (yt [n][s][c])
    ushort_t* xtb    = (ushort_t*)(ws + 46792960);     // 33,554,432 B
    const size_t BASE = 46792960ULL + 33554432ULL;     // 80,347,392
    ushort_t* qkvbuf = (ushort_t*)(ws + BASE);

    const size_t PER_HS = (size_t)3 * 64 * SS * 2;     // 1,572,864 per (sample, head)
    size_t avail = ws_size > BASE ? ws_size - BASE : 0;
    int NC = 1, HC = 1;
    if      (avail >= 64 * PER_HS) { NC = 8; HC = 8; }
    else if (avail >= 32 * PER_HS) { NC = 4; HC = 8; }
    else if (avail >= 16 * PER_HS) { NC = 2; HC = 8; }
    else if (avail >=  8 * PER_HS) { NC = 1; HC = 8; }
    else if (avail >=  4 * PER_HS) { NC = 1; HC = 4; }
    else if (avail >=  2 * PER_HS) { NC = 1; HC = 2; }

    probe_kernel <<<1, 64, 0, stream>>>((const unsigned int*)x, flag);
    ada_kernel   <<<dim3(NB, 4),  256, 0, stream>>>(cond, W_ada, b_ada, ada, flag);
    stats_kernel <<<dim3(NB, 64), 256, 0, stream>>>(x, part, flag);
    coef_kernel  <<<dim3(NB, 2),  256, 0, stream>>>(ada, part, coefA, coefB);
    wprime_kernel<<<dim3(NB, 6),  256, 0, stream>>>(W_qkv, b_qkv, coefA, coefB, wprime, bias2, flag);
    wconv_kernel <<<dim3(128),    256, 0, stream>>>(W_out, woutb, flag);
    xt_kernel    <<<dim3(512, NB), 256, 0, stream>>>(x, xtb, flag);

    for (int nb = 0; nb < NB; nb += NC)
        for (int hb = 0; hb < NHD; hb += HC) {
            qkv_gemm_kernel<<<dim3(NC, 64, HC), 256, 0, stream>>>(
                wprime, xtb, bias2, qkvbuf, nb, hb, HC);
            attn_kernel<<<dim3(32, HC, NC), 256, 0, stream>>>(
                qkvbuf, ybuf, nb, hb, HC);
        }

    out_gemm_kernel<<<dim3(64, NB), 512, 0, stream>>>(woutb, b_out, x, ybuf, out, flag);
}